// Round 1
// baseline (44.207 us; speedup 1.0000x reference)
//
#include <hip/hip_runtime.h>
#include <stdint.h>

typedef unsigned long long u64;

#define IN_FEATURES 256
#define UNITS 256
#define ROWS_PER_BLOCK 64

// ---------------------------------------------------------------------------
// Kernel 1: pack sign/nonzero bitplanes of w columns.
// w is [256][256] row-major (in_features x units). For column j we need bits
// over k = 0..255. Word t (t=0..3) covers k = 64t .. 64t+63.
// Layout in ws (u64*): wp[t*256 + j] = sign bits, wp[1024 + t*256 + j] = nz bits.
// grid = 4 blocks (one per word t), block = 256 threads (one per column j).
// Loads w[(t*64+b)*256 + j]: coalesced across j for each b.
// ---------------------------------------------------------------------------
__global__ __launch_bounds__(256) void pack_w_kernel(const float* __restrict__ w,
                                                     u64* __restrict__ wp) {
    const int t = blockIdx.x;    // word 0..3
    const int j = threadIdx.x;   // column 0..255
    u64 s = 0, z = 0;
#pragma unroll
    for (int b = 0; b < 64; ++b) {
        const float v = w[(t * 64 + b) * UNITS + j];
        s |= ((u64)(v < 0.0f)) << b;
        z |= ((u64)(v != 0.0f)) << b;
    }
    wp[t * UNITS + j] = s;
    wp[1024 + t * UNITS + j] = z;
}

// ---------------------------------------------------------------------------
// Kernel 2: main binary-dense.
// Block = 256 threads (4 waves), owns ROWS_PER_BLOCK=64 rows of x / out.
// Phase A: each wave packs 16 rows of x into LDS bitplanes via __ballot
//          (batched coalesced 256B loads per (row, word) to hide latency).
// Phase B: thread j owns output column j; its 8 w-words live in registers;
//          loop over 64 rows: broadcast LDS reads of the row's 8 words,
//          popcount arithmetic, coalesced 1KB row store.
// LOCAL_W variant packs w per-block (used only if ws is too small).
// ---------------------------------------------------------------------------
template <bool LOCAL_W>
__global__ __launch_bounds__(256) void binary_dense_kernel(const float* __restrict__ x,
                                                           const float* __restrict__ w,
                                                           const u64* __restrict__ wp,
                                                           float* __restrict__ out) {
    __shared__ u64 xs[ROWS_PER_BLOCK * 4];  // sign bits, [row*4 + t]
    __shared__ u64 xz[ROWS_PER_BLOCK * 4];  // nonzero bits

    const int tid = threadIdx.x;
    const int lane = tid & 63;
    const int wid = tid >> 6;  // wave id 0..3
    const long row0 = (long)blockIdx.x * ROWS_PER_BLOCK;

    // --- load (or build) this thread's column bitplanes into registers ---
    const int j = tid;  // column
    u64 ws_[4], wz_[4];
    if (LOCAL_W) {
        u64 s[4] = {0, 0, 0, 0}, z[4] = {0, 0, 0, 0};
#pragma unroll 4
        for (int k = 0; k < IN_FEATURES; ++k) {
            const float v = w[k * UNITS + j];  // coalesced across j
            s[k >> 6] |= ((u64)(v < 0.0f)) << (k & 63);
            z[k >> 6] |= ((u64)(v != 0.0f)) << (k & 63);
        }
#pragma unroll
        for (int t = 0; t < 4; ++t) { ws_[t] = s[t]; wz_[t] = z[t]; }
    } else {
#pragma unroll
        for (int t = 0; t < 4; ++t) {
            ws_[t] = wp[t * UNITS + j];
            wz_[t] = wp[1024 + t * UNITS + j];
        }
    }

    // --- Phase A: pack 16 rows per wave ---
    const int rbase = wid * 16;
#pragma unroll
    for (int t = 0; t < 4; ++t) {
        float v[16];
#pragma unroll
        for (int r = 0; r < 16; ++r) {
            v[r] = x[(row0 + rbase + r) * IN_FEATURES + t * 64 + lane];
        }
#pragma unroll
        for (int r = 0; r < 16; ++r) {
            const u64 s = __ballot(v[r] < 0.0f);
            const u64 z = __ballot(v[r] != 0.0f);
            if (lane == 0) {
                xs[(rbase + r) * 4 + t] = s;
                xz[(rbase + r) * 4 + t] = z;
            }
        }
    }
    __syncthreads();

    // --- Phase B: each thread computes column j for all 64 rows ---
#pragma unroll 4
    for (int r = 0; r < ROWS_PER_BLOCK; ++r) {
        int cnt_nz = 0, cnt_neg = 0;
#pragma unroll
        for (int t = 0; t < 4; ++t) {
            const u64 rs = xs[r * 4 + t];  // wave-uniform -> LDS broadcast
            const u64 rz = xz[r * 4 + t];
            const u64 nz = rz & wz_[t];
            const u64 d = (rs ^ ws_[t]) & nz;
            cnt_nz += __popcll(nz);
            cnt_neg += __popcll(d);
        }
        out[(row0 + r) * UNITS + j] = (float)(cnt_nz - 2 * cnt_neg);
    }
}

extern "C" void kernel_launch(void* const* d_in, const int* in_sizes, int n_in,
                              void* d_out, int out_size, void* d_ws, size_t ws_size,
                              hipStream_t stream) {
    const float* x = (const float*)d_in[0];
    const float* w = (const float*)d_in[1];
    float* out = (float*)d_out;

    const int batch = in_sizes[0] / IN_FEATURES;  // 65536
    const int nblocks = batch / ROWS_PER_BLOCK;   // 1024

    if (ws_size >= 2048 * sizeof(u64)) {
        u64* wp = (u64*)d_ws;
        pack_w_kernel<<<4, 256, 0, stream>>>(w, wp);
        binary_dense_kernel<false><<<nblocks, 256, 0, stream>>>(x, w, wp, out);
    } else {
        binary_dense_kernel<true><<<nblocks, 256, 0, stream>>>(x, w, nullptr, out);
    }
}

// Round 2
// 40.933 us; speedup vs baseline: 1.0800x; 1.0800x over previous
//
#include <hip/hip_runtime.h>
#include <stdint.h>

typedef unsigned long long u64;

#define IN_FEATURES 256
#define UNITS 256
#define ROWS_PER_WAVE 8
#define WAVES_PER_BLOCK 4
#define ROWS_PER_BLOCK (ROWS_PER_WAVE * WAVES_PER_BLOCK)  // 32

// ---------------------------------------------------------------------------
// Permuted bit layout (same permutation for x and w, so the dot product is
// unchanged): word t (0..3), bit b (0..63)  <->  feature k = 4*b + t.
// This makes x-packing trivial: lane l loads float4 at k=4l..4l+3; component t
// across 64 lanes is exactly word t via __ballot.
//
// wp layout (u64*): sign bits wp[c*4 + t], nonzero bits wp[1024 + c*4 + t]
// (c = output column). Per-lane w reads are then 128B contiguous.
// ---------------------------------------------------------------------------
__global__ __launch_bounds__(256) void pack_w_kernel(const float* __restrict__ w,
                                                     u64* __restrict__ wp) {
    const int t = blockIdx.x;    // word 0..3
    const int j = threadIdx.x;   // column 0..255
    u64 s = 0, z = 0;
#pragma unroll
    for (int b = 0; b < 64; ++b) {
        const float v = w[(4 * b + t) * UNITS + j];  // coalesced across j
        s |= ((u64)(v < 0.0f)) << b;
        z |= ((u64)(v != 0.0f)) << b;
    }
    wp[j * 4 + t] = s;
    wp[1024 + j * 4 + t] = z;
}

// ---------------------------------------------------------------------------
// Main kernel: no LDS, no barriers. Each wave owns ROWS_PER_WAVE rows.
// Lane l owns output columns 4l..4l+3 (w bitplanes in registers).
// Per row: one float4 load -> 8 ballots (SGPR-uniform row words) -> popcount
// arithmetic -> one coalesced dwordx4 store of 4 output floats.
// ---------------------------------------------------------------------------
__global__ __launch_bounds__(256) void binary_dense_kernel(const float4* __restrict__ x4,
                                                           const u64* __restrict__ wp,
                                                           float4* __restrict__ out4) {
    const int tid = threadIdx.x;
    const int lane = tid & 63;
    const int wid = tid >> 6;
    const long row0 = (long)blockIdx.x * ROWS_PER_BLOCK + (long)wid * ROWS_PER_WAVE;

    // w bitplanes for this lane's 4 columns: 32 u64 in registers.
    u64 ws_[4][4], wz_[4][4];
#pragma unroll
    for (int i = 0; i < 4; ++i) {
#pragma unroll
        for (int t = 0; t < 4; ++t) {
            ws_[i][t] = wp[(4 * lane + i) * 4 + t];
            wz_[i][t] = wp[1024 + (4 * lane + i) * 4 + t];
        }
    }

#pragma unroll
    for (int r = 0; r < ROWS_PER_WAVE; ++r) {
        const float4 v = x4[(row0 + r) * (IN_FEATURES / 4) + lane];

        u64 rs[4], rz[4];
        rs[0] = __ballot(v.x < 0.0f);
        rz[0] = __ballot(v.x != 0.0f);
        rs[1] = __ballot(v.y < 0.0f);
        rz[1] = __ballot(v.y != 0.0f);
        rs[2] = __ballot(v.z < 0.0f);
        rz[2] = __ballot(v.z != 0.0f);
        rs[3] = __ballot(v.w < 0.0f);
        rz[3] = __ballot(v.w != 0.0f);

        float o[4];
#pragma unroll
        for (int i = 0; i < 4; ++i) {
            int nzc = 0, ngc = 0;
#pragma unroll
            for (int t = 0; t < 4; ++t) {
                const u64 nz = rz[t] & wz_[i][t];          // uniform & vector
                const u64 d = (rs[t] ^ ws_[i][t]) & nz;
                nzc += __popcll(nz);
                ngc += __popcll(d);
            }
            o[i] = (float)(nzc - 2 * ngc);
        }
        out4[(row0 + r) * (UNITS / 4) + lane] = make_float4(o[0], o[1], o[2], o[3]);
    }
}

extern "C" void kernel_launch(void* const* d_in, const int* in_sizes, int n_in,
                              void* d_out, int out_size, void* d_ws, size_t ws_size,
                              hipStream_t stream) {
    const float* x = (const float*)d_in[0];
    const float* w = (const float*)d_in[1];
    float* out = (float*)d_out;

    const int batch = in_sizes[0] / IN_FEATURES;       // 65536
    const int nblocks = batch / ROWS_PER_BLOCK;        // 2048

    u64* wp = (u64*)d_ws;  // needs 16 KB; ws is preallocated scratch
    pack_w_kernel<<<4, 256, 0, stream>>>(w, wp);
    binary_dense_kernel<<<nblocks, 256, 0, stream>>>((const float4*)x, wp, (float4*)out);
}

// Round 3
// 39.595 us; speedup vs baseline: 1.1165x; 1.0338x over previous
//
#include <hip/hip_runtime.h>
#include <stdint.h>

typedef unsigned long long u64;
typedef __attribute__((ext_vector_type(8))) short bf16x8;   // 8 bf16 (4 VGPRs)
typedef __attribute__((ext_vector_type(4))) float f32x4;    // MFMA acc

#define IN_FEATURES 256
#define UNITS 256
#define BM 64          // rows per block (main kernel)
#define LDK 264        // padded LDS stride in ushorts (528 B: 4-bank rotation/row)

// sign(x) as bf16 bits: 0 for ±0, else ±1.0 (0x3F80 | signbit). Exact.
__device__ __forceinline__ ushort sgn_bf16(float f) {
    uint u = __float_as_uint(f);
    return ((u << 1) == 0u) ? (ushort)0 : (ushort)(0x3F80u | ((u >> 16) & 0x8000u));
}
__device__ __forceinline__ uint sgn_pack2(float a, float b) {
    return (uint)sgn_bf16(a) | ((uint)sgn_bf16(b) << 16);
}

// ---------------------------------------------------------------------------
// Pack kernel: wB[col][k] = sign-bf16 of w[k][col]  (transpose via LDS).
// 16 blocks x 256 threads; block b owns cols b*16..b*16+15.
// ---------------------------------------------------------------------------
__global__ __launch_bounds__(256) void pack_w_bf16(const float* __restrict__ w,
                                                   ushort* __restrict__ wB) {
    __shared__ ushort ls[256][18];  // [k][c], +2 pad
    const int b = blockIdx.x;
    const int t = threadIdx.x;

    // Phase 1: thread t reads row k=t, cols b*16..+15 (4x float4, 64B)
    const float4* wr = (const float4*)(w + (size_t)t * UNITS + b * 16);
#pragma unroll
    for (int i = 0; i < 4; ++i) {
        const float4 v = wr[i];
        ls[t][i * 4 + 0] = sgn_bf16(v.x);
        ls[t][i * 4 + 1] = sgn_bf16(v.y);
        ls[t][i * 4 + 2] = sgn_bf16(v.z);
        ls[t][i * 4 + 3] = sgn_bf16(v.w);
    }
    __syncthreads();

    // Phase 2: thread t writes col c = b*16 + (t>>4), k-chunk (t&15)*16 (32B)
    const int c = t >> 4;
    const int k0 = (t & 15) * 16;
    alignas(16) ushort tmp[16];
#pragma unroll
    for (int i = 0; i < 16; ++i) tmp[i] = ls[k0 + i][c];
    ushort* dst = wB + ((size_t)(b * 16 + c)) * IN_FEATURES + k0;
    *(uint4*)(dst) = *(const uint4*)&tmp[0];
    *(uint4*)(dst + 8) = *(const uint4*)&tmp[8];
}

// ---------------------------------------------------------------------------
// Main kernel: bf16 MFMA GEMM, M-tile 64 per block, full N=256.
// 4 waves: wave w owns 64 rows x cols [w*64, w*64+64) = 4x4 16x16 tiles.
// Stage x rows once into LDS as sign-bf16 (padded stride), then 8 k-steps.
// B fragments stream from wB (L2-resident, 128 KB).
// ---------------------------------------------------------------------------
__global__ __launch_bounds__(256, 2) void bdense_mfma(const float4* __restrict__ x4,
                                                      const ushort* __restrict__ wB,
                                                      float* __restrict__ out) {
    __shared__ ushort xs[BM][LDK];  // 33792 B

    const int tid = threadIdx.x;
    const int lane = tid & 63;
    const int wid = tid >> 6;
    const long row0 = (long)blockIdx.x * BM;

    // --- stage: 64 rows x 256 k, fully coalesced float4 loads ---
#pragma unroll
    for (int i = 0; i < 16; ++i) {
        const int f = i * 256 + tid;     // flat float4 index within tile
        const int r = f >> 6;            // row 0..63
        const int kq = (f & 63);         // float4 index within row
        const float4 v = x4[(row0 + r) * (IN_FEATURES / 4) + kq];
        const uint u0 = sgn_pack2(v.x, v.y);
        const uint u1 = sgn_pack2(v.z, v.w);
        *(uint2*)&xs[r][kq * 4] = make_uint2(u0, u1);
    }
    __syncthreads();

    f32x4 acc[4][4];
#pragma unroll
    for (int mt = 0; mt < 4; ++mt)
#pragma unroll
        for (int nt = 0; nt < 4; ++nt) acc[mt][nt] = (f32x4){0.f, 0.f, 0.f, 0.f};

    const int colbase = wid * 64;
    const int rlane = lane & 15;

#pragma unroll
    for (int ks = 0; ks < 8; ++ks) {
        const int klane = ks * 32 + (lane >> 4) * 8;  // this lane's 8-k chunk

        bf16x8 a[4], bf[4];
#pragma unroll
        for (int mt = 0; mt < 4; ++mt)
            a[mt] = *(const bf16x8*)&xs[mt * 16 + rlane][klane];   // ds_read_b128
#pragma unroll
        for (int nt = 0; nt < 4; ++nt) {
            const int col = colbase + nt * 16 + rlane;
            bf[nt] = *(const bf16x8*)&wB[(size_t)col * IN_FEATURES + klane];  // 16B
        }
#pragma unroll
        for (int mt = 0; mt < 4; ++mt)
#pragma unroll
            for (int nt = 0; nt < 4; ++nt)
                acc[mt][nt] = __builtin_amdgcn_mfma_f32_16x16x32_bf16(
                    a[mt], bf[nt], acc[mt][nt], 0, 0, 0);
    }

    // --- store: C/D map col=lane&15, row=(lane>>4)*4+reg (m89-verified) ---
    const int crow = (lane >> 4) * 4;
#pragma unroll
    for (int mt = 0; mt < 4; ++mt) {
#pragma unroll
        for (int nt = 0; nt < 4; ++nt) {
            float* op = out + (row0 + mt * 16 + crow) * UNITS + colbase + nt * 16 + rlane;
#pragma unroll
            for (int j = 0; j < 4; ++j) op[j * UNITS] = acc[mt][nt][j];
        }
    }
}

// ---------------------------------------------------------------------------
// Fallback (ws too small): round-2 popcount path, known-correct.
// ---------------------------------------------------------------------------
__global__ __launch_bounds__(256) void pack_w_bits(const float* __restrict__ w,
                                                   u64* __restrict__ wp) {
    const int t = blockIdx.x;
    const int j = threadIdx.x;
    u64 s = 0, z = 0;
#pragma unroll
    for (int b = 0; b < 64; ++b) {
        const float v = w[(4 * b + t) * UNITS + j];
        s |= ((u64)(v < 0.0f)) << b;
        z |= ((u64)(v != 0.0f)) << b;
    }
    wp[j * 4 + t] = s;
    wp[1024 + j * 4 + t] = z;
}

__global__ __launch_bounds__(256) void bdense_pop(const float4* __restrict__ x4,
                                                  const u64* __restrict__ wp,
                                                  float4* __restrict__ out4) {
    const int tid = threadIdx.x;
    const int lane = tid & 63;
    const int wid = tid >> 6;
    const long row0 = (long)blockIdx.x * 32 + (long)wid * 8;

    u64 ws_[4][4], wz_[4][4];
#pragma unroll
    for (int i = 0; i < 4; ++i)
#pragma unroll
        for (int t = 0; t < 4; ++t) {
            ws_[i][t] = wp[(4 * lane + i) * 4 + t];
            wz_[i][t] = wp[1024 + (4 * lane + i) * 4 + t];
        }

#pragma unroll
    for (int r = 0; r < 8; ++r) {
        const float4 v = x4[(row0 + r) * (IN_FEATURES / 4) + lane];
        u64 rs[4], rz[4];
        rs[0] = __ballot(v.x < 0.0f); rz[0] = __ballot(v.x != 0.0f);
        rs[1] = __ballot(v.y < 0.0f); rz[1] = __ballot(v.y != 0.0f);
        rs[2] = __ballot(v.z < 0.0f); rz[2] = __ballot(v.z != 0.0f);
        rs[3] = __ballot(v.w < 0.0f); rz[3] = __ballot(v.w != 0.0f);
        float o[4];
#pragma unroll
        for (int i = 0; i < 4; ++i) {
            int nzc = 0, ngc = 0;
#pragma unroll
            for (int t = 0; t < 4; ++t) {
                const u64 nz = rz[t] & wz_[i][t];
                const u64 d = (rs[t] ^ ws_[i][t]) & nz;
                nzc += __popcll(nz);
                ngc += __popcll(d);
            }
            o[i] = (float)(nzc - 2 * ngc);
        }
        out4[(row0 + r) * (UNITS / 4) + lane] = make_float4(o[0], o[1], o[2], o[3]);
    }
}

extern "C" void kernel_launch(void* const* d_in, const int* in_sizes, int n_in,
                              void* d_out, int out_size, void* d_ws, size_t ws_size,
                              hipStream_t stream) {
    const float* x = (const float*)d_in[0];
    const float* w = (const float*)d_in[1];
    float* out = (float*)d_out;

    const int batch = in_sizes[0] / IN_FEATURES;  // 65536

    if (ws_size >= (size_t)UNITS * IN_FEATURES * sizeof(ushort)) {  // 128 KB
        ushort* wB = (ushort*)d_ws;
        pack_w_bf16<<<16, 256, 0, stream>>>(w, wB);
        bdense_mfma<<<batch / BM, 256, 0, stream>>>((const float4*)x, wB, out);
    } else {
        u64* wp = (u64*)d_ws;  // 16 KB
        pack_w_bits<<<4, 256, 0, stream>>>(w, wp);
        bdense_pop<<<batch / 32, 256, 0, stream>>>((const float4*)x, wp, (float4*)out);
    }
}